// Round 3
// baseline (135.076 us; speedup 1.0000x reference)
//
#include <hip/hip_runtime.h>
#include <stdint.h>

// AWQGemm: x[1024,4096] f32, qweight[4096,1376] i32, scales[32,11008] f32,
// qzeros[32,1376] i32 -> C[1024,11008] f32
#define M_DIM 1024
#define K_DIM 4096
#define N_DIM 11008
#define NC_DIM 1376
#define G_DIM 32
#define GS 128

typedef __bf16 bf16x8 __attribute__((ext_vector_type(8)));
typedef float f32x16 __attribute__((ext_vector_type(16)));
typedef unsigned short ushort8 __attribute__((ext_vector_type(8)));

typedef __attribute__((address_space(1))) char as1_char;
typedef __attribute__((address_space(3))) char as3_char;
#define GLDS16(g, l) __builtin_amdgcn_global_load_lds((as1_char*)(g), (as3_char*)(l), 16, 0, 0)

static __device__ __forceinline__ int awq_shift(int j) {
  return ((j & 1) << 4) | ((j >> 1) << 2);
}

// fp32 -> bf16 bits, RNE
static __device__ __forceinline__ unsigned short f2bf(float f) {
  union { float f; uint32_t u; } c; c.f = f;
  uint32_t u = c.u;
  return (unsigned short)((u + 0x7FFFu + ((u >> 16) & 1u)) >> 16);
}

// ---------------- Stage 0: x fp32 -> bf16 ----------------
__global__ void k_cvt_x(const float* __restrict__ x, unsigned short* __restrict__ xb) {
  int i = blockIdx.x * blockDim.x + threadIdx.x;
  int base = i * 8;
  float4 v0 = *(const float4*)(x + base);
  float4 v1 = *(const float4*)(x + base + 4);
  ushort8 o;
  o[0] = f2bf(v0.x); o[1] = f2bf(v0.y); o[2] = f2bf(v0.z); o[3] = f2bf(v0.w);
  o[4] = f2bf(v1.x); o[5] = f2bf(v1.y); o[6] = f2bf(v1.z); o[7] = f2bf(v1.w);
  *(ushort8*)(xb + base) = o;
}

// ---------------- Stage 1: dequant W -> W^T bf16 [N][K] ----------------
__global__ void k_dequant(const int* __restrict__ qw, const float* __restrict__ scales,
                          const int* __restrict__ qz, unsigned short* __restrict__ wt) {
  __shared__ int wlds[64][17];
  const int t = threadIdx.x;
  const int k0 = blockIdx.x * 64;
  const int nb = blockIdx.y;
  const int n_glob0 = nb * 128;
  const int c0 = n_glob0 >> 3;
  const int g = k0 >> 7;
#pragma unroll
  for (int p = 0; p < 4; ++p) {
    int idx = p * 256 + t;
    int k = idx >> 4, c = idx & 15;
    wlds[k][c] = qw[(size_t)(k0 + k) * NC_DIM + c0 + c];
  }
  __syncthreads();
#pragma unroll
  for (int p = 0; p < 4; ++p) {
    int u = p * 256 + t;
    int k8 = u & 7;
    int nl = u >> 3;
    int j = nl & 7;
    int c = nl >> 3;
    int shift = awq_shift(j);
    float s = scales[(size_t)g * N_DIM + n_glob0 + nl];
    int zw = qz[(size_t)g * NC_DIM + c0 + c];
    float zs = (float)((zw >> shift) & 0xF) * s;
    ushort8 o;
#pragma unroll
    for (int i = 0; i < 8; ++i) {
      int wv = wlds[k8 * 8 + i][c];
      int nib = (wv >> shift) & 0xF;
      o[i] = f2bf(fmaf((float)nib, s, -zs));
    }
    *(ushort8*)(wt + (size_t)(nb * 128 + nl) * K_DIM + k0 + k8 * 8) = o;
  }
}

// ---------------- Stage 2: 256x256 8-phase bf16 GEMM, 32x32x16 MFMA ----------
// Identical schedule/barriers/vmcnt/swizzle to R2 (verified race-free).
// Changes vs R2: MFMA shape 16x16x32 -> 32x32x16 (15% faster matrix pipe),
// staging addresses hoisted to per-lane base pointers, B read before A in p0.
// 8 waves (2M x 4N); per-wave out 128x64 = 4 rb x 2 cb of 32x32; acc f32x16[4][2].
#define BK 64
#define NT (K_DIM / BK)
#define REG_BYTES 16384

#define RD(base, off) (*(const bf16x8*)((const unsigned char*)(base) + (off)))
#define MFMA32(a, b, c) __builtin_amdgcn_mfma_f32_32x32x16_bf16((a), (b), (c), 0, 0, 0)

__launch_bounds__(512, 2)
__global__ void k_gemm8(const unsigned short* __restrict__ A,
                        const unsigned short* __restrict__ Bt,
                        float* __restrict__ C) {
  __shared__ __attribute__((aligned(16))) unsigned char LDS[131072];

  const int tid = threadIdx.x;
  const int lane = tid & 63;
  const int w = tid >> 6;       // 0..7
  const int wm = w >> 2;        // 0..1  (M half: rows wm*128..+128)
  const int wn = w & 3;         // 0..3  (N quarter: cols wn*64..+64)
  const int r32 = lane & 31;    // row within 32-row MFMA block
  const int hh = lane >> 5;     // 0..1  (k-half of fragment)

  // swizzled k-byte positions for the 4 K=16 sub-steps of a 64-k row (128B)
  const int xorr = (lane & 7) << 4;
  int kpos[4];
#pragma unroll
  for (int ks = 0; ks < 4; ++ks) kpos[ks] = ((ks << 5) | (hh << 4)) ^ xorr;

  // bijective XCD swizzle: nwg=172 = 8*21+4
  const int orig = blockIdx.x;
  const int xcd = orig & 7, loc = orig >> 3;
  const int qq = 21, rr = 4;
  const int swz = (xcd < rr) ? xcd * (qq + 1) + loc : rr * (qq + 1) + (xcd - rr) * qq + loc;
  const int m0 = (swz & 3) * 256;    // M fastest: 4 row-tiles share a B panel per XCD chunk
  const int nb0 = (swz >> 2) * 256;

  // ---- hoisted staging addresses (semantics identical to R2's stage_half) ----
  const int kb_src = (((lane & 7) ^ ((lane >> 3) & 7)) << 4) >> 1;  // element offset
  const int srow = w * 16 + (lane >> 3);
  const unsigned short* gA0 = A + (size_t)(m0 + srow) * K_DIM + kb_src;
  const unsigned short* gA1 = gA0 + (size_t)128 * K_DIM;
  const unsigned short* gB0 = Bt + (size_t)(nb0 + srow) * K_DIM + kb_src;
  const unsigned short* gB1 = gB0 + (size_t)128 * K_DIM;
  const int ldsw = w * 2048;  // wave-uniform LDS dest; HW adds lane*16

#define STAGE(gp, T, bufoff, region)                                              \
  do {                                                                            \
    const unsigned short* _g = (gp) + (size_t)(T) * 64;                           \
    unsigned char* _l = LDS + (bufoff) + (region) * REG_BYTES + ldsw;             \
    GLDS16(_g, _l);                                                               \
    GLDS16(_g + (size_t)8 * K_DIM, _l + 1024);                                    \
  } while (0)

  f32x16 acc[4][2] = {};

  // ---- prologue: tile0 all 4 halves, then B0(1), A0(1); vmcnt(4); barrier ----
  STAGE(gA0, 0, 0, 0);
  STAGE(gA1, 0, 0, 1);
  STAGE(gB0, 0, 0, 2);
  STAGE(gB1, 0, 0, 3);
  STAGE(gB0, 1, 65536, 2);
  STAGE(gA0, 1, 65536, 0);
  asm volatile("s_waitcnt vmcnt(4)" ::: "memory");
  __builtin_amdgcn_s_barrier();

#pragma unroll 2
  for (int t = 0; t < NT; ++t) {
    const int cur = t & 1;
    const int bo_c = cur * 65536;
    const int bo_n = (cur ^ 1) * 65536;
    const unsigned char* rdA = LDS + bo_c + wm * REG_BYTES + r32 * 128;
    const unsigned char* rdB = LDS + bo_c + (2 + (wn >> 1)) * REG_BYTES + (wn & 1) * 8192 + r32 * 128;

    bf16x8 aF[2][4], bA[4], bB[4];

    // ---------- phase 0: read B(cb0), A(rb0), A(rb1); stage A1(t+1) ----------
#pragma unroll
    for (int ks = 0; ks < 4; ++ks) bA[ks] = RD(rdB, kpos[ks]);
#pragma unroll
    for (int rb = 0; rb < 2; ++rb)
#pragma unroll
      for (int ks = 0; ks < 4; ++ks) aF[rb][ks] = RD(rdA, rb * 4096 + kpos[ks]);
    if (t + 1 < NT) STAGE(gA1, t + 1, bo_n, 1);
    __builtin_amdgcn_s_barrier();
    __builtin_amdgcn_s_setprio(1);
#pragma unroll
    for (int ks = 0; ks < 4; ++ks) {
      acc[0][0] = MFMA32(aF[0][ks], bA[ks], acc[0][0]);
      acc[1][0] = MFMA32(aF[1][ks], bA[ks], acc[1][0]);
    }
    __builtin_amdgcn_s_setprio(0);
    __builtin_amdgcn_s_barrier();

    // ---------- phase 1: read B(cb1); stage B1(t+1) ----------
#pragma unroll
    for (int ks = 0; ks < 4; ++ks) bB[ks] = RD(rdB, 4096 + kpos[ks]);
    if (t + 1 < NT) STAGE(gB1, t + 1, bo_n, 3);
    __builtin_amdgcn_s_barrier();
    __builtin_amdgcn_s_setprio(1);
#pragma unroll
    for (int ks = 0; ks < 4; ++ks) {
      acc[0][1] = MFMA32(aF[0][ks], bB[ks], acc[0][1]);
      acc[1][1] = MFMA32(aF[1][ks], bB[ks], acc[1][1]);
    }
    __builtin_amdgcn_s_setprio(0);
    __builtin_amdgcn_s_barrier();

    // ---------- phase 2: read A(rb2), A(rb3); stage B0(t+2) ----------
#pragma unroll
    for (int rb = 0; rb < 2; ++rb)
#pragma unroll
      for (int ks = 0; ks < 4; ++ks) aF[rb][ks] = RD(rdA, (rb + 2) * 4096 + kpos[ks]);
    if (t + 2 < NT) STAGE(gB0, t + 2, bo_c, 2);
    __builtin_amdgcn_s_barrier();
    __builtin_amdgcn_s_setprio(1);
#pragma unroll
    for (int ks = 0; ks < 4; ++ks) {
      acc[2][1] = MFMA32(aF[0][ks], bB[ks], acc[2][1]);
      acc[3][1] = MFMA32(aF[1][ks], bB[ks], acc[3][1]);
    }
    __builtin_amdgcn_s_setprio(0);
    __builtin_amdgcn_s_barrier();

    // ---------- phase 3: stage A0(t+2); counted vmcnt ----------
    if (t + 2 < NT) STAGE(gA0, t + 2, bo_c, 0);
    __builtin_amdgcn_s_barrier();
    __builtin_amdgcn_s_setprio(1);
#pragma unroll
    for (int ks = 0; ks < 4; ++ks) {
      acc[2][0] = MFMA32(aF[0][ks], bA[ks], acc[2][0]);
      acc[3][0] = MFMA32(aF[1][ks], bA[ks], acc[3][0]);
    }
    __builtin_amdgcn_s_setprio(0);
    if (t < NT - 2) {
      asm volatile("s_waitcnt vmcnt(4)" ::: "memory");
    } else {
      asm volatile("s_waitcnt vmcnt(0)" ::: "memory");
    }
    __builtin_amdgcn_s_barrier();
  }

  // ---- epilogue: 32x32 C/D map col=lane&31, row=(reg&3)+8*(reg>>2)+4*(lane>>5)
  const int ccol = nb0 + wn * 64 + r32;
  const int crow_base = m0 + wm * 128 + 4 * hh;
#pragma unroll
  for (int rb = 0; rb < 4; ++rb)
#pragma unroll
    for (int cb = 0; cb < 2; ++cb) {
      f32x16 v = acc[rb][cb];
#pragma unroll
      for (int reg = 0; reg < 16; ++reg) {
        int row = crow_base + rb * 32 + (reg & 3) + 8 * (reg >> 2);
        C[(size_t)row * N_DIM + ccol + cb * 32] = v[reg];
      }
    }
}

// ---------------- Fallback (ws too small) ----------------
__global__ void k_fallback(const float* __restrict__ x, const int* __restrict__ qw,
                           const float* __restrict__ scales, const int* __restrict__ qz,
                           float* __restrict__ C) {
  int t = blockIdx.x * 256 + threadIdx.x;
  int m = t / NC_DIM;
  int c = t % NC_DIM;
  float acc[8];
#pragma unroll
  for (int j = 0; j < 8; ++j) acc[j] = 0.f;
  for (int g = 0; g < G_DIM; ++g) {
    int zw = qz[(size_t)g * NC_DIM + c];
    float sj[8], zsj[8];
#pragma unroll
    for (int j = 0; j < 8; ++j) {
      sj[j] = scales[(size_t)g * N_DIM + c * 8 + j];
      zsj[j] = (float)((zw >> awq_shift(j)) & 0xF) * sj[j];
    }
    for (int k = g * GS; k < (g + 1) * GS; ++k) {
      float xv = x[(size_t)m * K_DIM + k];
      int wv = qw[(size_t)k * NC_DIM + c];
#pragma unroll
      for (int j = 0; j < 8; ++j) {
        float dq = fmaf((float)((wv >> awq_shift(j)) & 0xF), sj[j], -zsj[j]);
        acc[j] = fmaf(xv, dq, acc[j]);
      }
    }
  }
#pragma unroll
  for (int j = 0; j < 8; ++j)
    C[(size_t)m * N_DIM + c * 8 + j] = acc[j];
}

extern "C" void kernel_launch(void* const* d_in, const int* in_sizes, int n_in,
                              void* d_out, int out_size, void* d_ws, size_t ws_size,
                              hipStream_t stream) {
  (void)in_sizes; (void)n_in; (void)out_size;
  const float* x = (const float*)d_in[0];
  const int* qw = (const int*)d_in[1];
  const float* scales = (const float*)d_in[2];
  const int* qz = (const int*)d_in[3];
  float* C = (float*)d_out;

  const size_t xb_bytes = (size_t)M_DIM * K_DIM * 2;
  const size_t wt_bytes = (size_t)N_DIM * K_DIM * 2;

  if (ws_size >= xb_bytes + wt_bytes) {
    unsigned short* xb = (unsigned short*)d_ws;
    unsigned short* wt = (unsigned short*)((char*)d_ws + xb_bytes);
    k_cvt_x<<<(M_DIM * K_DIM) / (256 * 8), 256, 0, stream>>>(x, xb);
    dim3 gd(K_DIM / 64, N_DIM / 128);
    k_dequant<<<gd, 256, 0, stream>>>(qw, scales, qz, wt);
    k_gemm8<<<(M_DIM / 256) * (N_DIM / 256), 512, 0, stream>>>(xb, wt, C);
  } else {
    k_fallback<<<(M_DIM * NC_DIM) / 256, 256, 0, stream>>>(x, qw, scales, qz, C);
  }
}